// Round 12
// baseline (411.096 us; speedup 1.0000x reference)
//
#include <hip/hip_runtime.h>

// ---------------------------------------------------------------------------
// Mamba block. fp32 in/out. Internal: bf16 MFMA operands, fp32 accumulation
// and scan state.
// R12: gemm1 tile 128x256 (NW=8): halves blocks/barrier-drains, amortizes
// prologue/epilogue (K=1024 -> only 16 K-steps; overhead was ~25% of block
// life at 128x128). Launch count 12->10: w2bf(W_in) merged into ln grid,
// xdbl memset folded into conv.
// ---------------------------------------------------------------------------
#define BATCH   2
#define SEQ     2048
#define DMODEL  1024
#define DINNER  2048
#define DSTATE  16
#define DTRANK  64
#define MROWS   (BATCH * SEQ)   // 4096
#define CLEN    64              // scan chunk length
#define CHUNKS  (SEQ / CLEN)    // 32

typedef float floatx4 __attribute__((ext_vector_type(4)));
typedef __bf16 bf16x8 __attribute__((ext_vector_type(8)));

__device__ __forceinline__ void async_cp16(void* lds, const void* g) {
    __builtin_amdgcn_global_load_lds((const __attribute__((address_space(1))) void*)g,
                                     (__attribute__((address_space(3))) void*)lds, 16, 0, 0);
}

// ---------------------------------------------------------------------------
// K1: prep = LayerNorm (blocks 0..4095) + W_in fp32->bf16 (blocks 4096..12287)
// ---------------------------------------------------------------------------
__global__ __launch_bounds__(256) void prep_kernel(const float* __restrict__ x,
                                                   const float* __restrict__ w,
                                                   const float* __restrict__ b,
                                                   __bf16* __restrict__ xn,
                                                   const float* __restrict__ Win,
                                                   __bf16* __restrict__ Winb) {
    if (blockIdx.x >= MROWS) {
        int i = ((blockIdx.x - MROWS) * 256 + threadIdx.x) * 4;
        floatx4 v = *(const floatx4*)&Win[i];
        __bf16 r[4];
#pragma unroll
        for (int t = 0; t < 4; ++t) r[t] = (__bf16)v[t];
        *(unsigned long long*)&Winb[i] = *(unsigned long long*)r;
        return;
    }
    int row = blockIdx.x;
    const float* xr = x + (size_t)row * DMODEL;
    float v[4], s = 0.f, ss = 0.f;
#pragma unroll
    for (int i = 0; i < 4; ++i) {
        v[i] = xr[threadIdx.x + i * 256];
        s += v[i]; ss += v[i] * v[i];
    }
#pragma unroll
    for (int o = 32; o > 0; o >>= 1) { s += __shfl_xor(s, o); ss += __shfl_xor(ss, o); }
    __shared__ float ps[4], pss[4];
    int wv = threadIdx.x >> 6;
    if ((threadIdx.x & 63) == 0) { ps[wv] = s; pss[wv] = ss; }
    __syncthreads();
    s  = ps[0] + ps[1] + ps[2] + ps[3];
    ss = pss[0] + pss[1] + pss[2] + pss[3];
    float mu  = s * (1.f / DMODEL);
    float var = ss * (1.f / DMODEL) - mu * mu;
    float rs  = rsqrtf(var + 1e-5f);
#pragma unroll
    for (int i = 0; i < 4; ++i) {
        int c = threadIdx.x + i * 256;
        xn[(size_t)row * DMODEL + c] = (__bf16)((v[i] - mu) * rs * w[c] + b[c]);
    }
}

// K0b: plain fp32 -> bf16 (for W_out, after pass3 when its region is dead)
__global__ __launch_bounds__(256) void w2bf(const float* __restrict__ w,
                                            __bf16* __restrict__ o, int n) {
    int i = (blockIdx.x * 256 + threadIdx.x) * 4;
    if (i < n) {
        floatx4 v = *(const floatx4*)&w[i];
        __bf16 r[4];
#pragma unroll
        for (int t = 0; t < 4; ++t) r[t] = (__bf16)v[t];
        *(unsigned long long*)&o[i] = *(unsigned long long*)r;
    }
}

// ---------------------------------------------------------------------------
// K2: async-staged MFMA GEMM.  C[M,N] = A[M,K] * B[N,K]^T, A,B bf16.
// Tile 128 x (NW*32), BK=64, 4 waves (2x2), wave = 64m x (NW*16)n.
// Chunk = 1 KiB = 8 rows x 128 B, source-side XOR swizzle (see R11).
// EPI=1: split -> out0 bf16 (n<split) / out1 bf16 (n>=split)
// EPI=2: residual -> outf fp32 = acc + add[idx]
// ---------------------------------------------------------------------------
template <int EPI, int NW>
__global__ __launch_bounds__(256) void gemm_as(const __bf16* __restrict__ A,
                                               const __bf16* __restrict__ Bb,
                                               int M, int N, int K,
                                               __bf16* __restrict__ out0,
                                               __bf16* __restrict__ out1,
                                               float* __restrict__ outf,
                                               const float* __restrict__ add,
                                               int split) {
    constexpr int BNT = NW * 32;
    constexpr int ACH = 16;                      // A chunks per K-step
    constexpr int NCH = ACH + BNT / 8;           // + B chunks
    __shared__ __align__(16) __bf16 sA[128 * 64];
    __shared__ __align__(16) __bf16 sB[BNT * 64];
    int tid  = threadIdx.x;
    int wave = tid >> 6, lane = tid & 63;
    int m0 = blockIdx.y * 128, n0 = blockIdx.x * BNT;
    int wm = (wave & 1) * 64, wn = (wave >> 1) * (NW * 16);
    int lr = lane & 15;
    int lq = lane >> 4;
    int srow = lane >> 3;                        // row within a chunk (0..7)
    int sg   = ((lane & 7) ^ srow) * 8;          // swizzled source elem group

    floatx4 acc[4][NW] = {};

    for (int k0 = 0; k0 < K; k0 += 64) {
        for (int c = wave; c < NCH; c += 4) {
            if (c < ACH) {
                const __bf16* g = A + (size_t)(m0 + c * 8 + srow) * K + k0 + sg;
                async_cp16(&sA[c * 512], g);
            } else {
                int cb = c - ACH;
                const __bf16* g = Bb + (size_t)(n0 + cb * 8 + srow) * K + k0 + sg;
                async_cp16(&sB[cb * 512], g);
            }
        }
        __syncthreads();

#pragma unroll
        for (int s = 0; s < 2; ++s) {
            bf16x8 af[4], bfr[NW];
#pragma unroll
            for (int i = 0; i < 4; ++i) {
                int row = wm + i * 16 + lr;
                af[i] = *(const bf16x8*)&sA[row * 64 + (((s * 4 + lq) ^ (lr & 7)) * 8)];
            }
#pragma unroll
            for (int j = 0; j < NW; ++j) {
                int row = wn + j * 16 + lr;
                bfr[j] = *(const bf16x8*)&sB[row * 64 + (((s * 4 + lq) ^ (lr & 7)) * 8)];
            }
#pragma unroll
            for (int i = 0; i < 4; ++i)
#pragma unroll
                for (int j = 0; j < NW; ++j)
                    acc[i][j] = __builtin_amdgcn_mfma_f32_16x16x32_bf16(af[i], bfr[j], acc[i][j], 0, 0, 0);
        }
        __syncthreads();
    }

#pragma unroll
    for (int i = 0; i < 4; ++i)
#pragma unroll
        for (int j = 0; j < NW; ++j) {
            int gn = n0 + wn + j * 16 + lr;
#pragma unroll
            for (int r = 0; r < 4; ++r) {
                int gm = m0 + wm + i * 16 + lq * 4 + r;
                float v = acc[i][j][r];
                if (EPI == 1) {
                    if (gn < split) out0[(size_t)gm * split + gn] = (__bf16)v;
                    else            out1[(size_t)gm * split + (gn - split)] = (__bf16)v;
                } else {
                    size_t idx = (size_t)gm * N + gn;
                    outf[idx] = v + add[idx];
                }
            }
        }
}

// ---------------------------------------------------------------------------
// K3: depthwise causal conv (width 4) + bias + SiLU.  Also zeroes xdbl
// (398K floats; xdbl sits in dead-xn region, wx runs after conv -> safe).
// ---------------------------------------------------------------------------
__global__ __launch_bounds__(256) void conv_kernel(const __bf16* __restrict__ xin,
                                                   const float* __restrict__ cw,
                                                   const float* __restrict__ cb,
                                                   __bf16* __restrict__ u,
                                                   float* __restrict__ xdbl) {
    int idx = blockIdx.x * 256 + threadIdx.x;        // over MROWS*DINNER
    if (idx < MROWS * 96 / 4) {
        floatx4 z = {0.f, 0.f, 0.f, 0.f};
        *(floatx4*)&xdbl[idx * 4] = z;
    }
    int d  = idx & (DINNER - 1);
    int bl = idx >> 11;                              // b*SEQ + l
    int l  = bl & (SEQ - 1);
    float acc = cb[d];
#pragma unroll
    for (int j = 0; j < 4; ++j) {
        int ll = l - 3 + j;
        if (ll >= 0) acc += (float)xin[(size_t)(bl - 3 + j) * DINNER + d] * cw[d * 4 + j];
    }
    float sg = 1.f / (1.f + __expf(-acc));
    u[idx] = (__bf16)(acc * sg);
}

// ---------------------------------------------------------------------------
// K4 (MFMA, split-K): xdbl[4096,96] += u[4096,2048] @ Wx[96,2048]^T.
// ---------------------------------------------------------------------------
#define BM 128
#define BN 128
#define BK 32
#define LDK 48
#define WX_KS 16
#define WX_KSLICE (DINNER / WX_KS)   // 128

__global__ __launch_bounds__(256) void wx_mfma(const __bf16* __restrict__ A,
                                               const float* __restrict__ B,
                                               float* __restrict__ xdbl) {
    __shared__ __align__(16) __bf16 sA[BM][LDK];
    __shared__ __align__(16) __bf16 sB[96][LDK];
    int tid  = threadIdx.x;
    int wave = tid >> 6, lane = tid & 63;
    int m0 = blockIdx.x * BM;
    int k0base = blockIdx.y * WX_KSLICE;
    int wm = (wave & 1) * 64, wn = (wave >> 1) * 48;
    int lr = lane & 15;
    int lq = lane >> 4;

    floatx4 acc[4][3] = {};

    for (int k0 = k0base; k0 < k0base + WX_KSLICE; k0 += BK) {
#pragma unroll
        for (int c = tid; c < 512; c += 256) {
            int row = c >> 2, col = (c & 3) * 8;
            *(bf16x8*)&sA[row][col] = *(const bf16x8*)&A[(size_t)(m0 + row) * DINNER + k0 + col];
        }
        for (int c = tid; c < 384; c += 256) {
            int row = c >> 2, col = (c & 3) * 8;
            const float* src = B + (size_t)row * DINNER + k0 + col;
            floatx4 lo = *(const floatx4*)src;
            floatx4 hi = *(const floatx4*)(src + 4);
            bf16x8 v;
#pragma unroll
            for (int t = 0; t < 4; ++t) { v[t] = (__bf16)lo[t]; v[4 + t] = (__bf16)hi[t]; }
            *(bf16x8*)&sB[row][col] = v;
        }
        __syncthreads();

        bf16x8 af[4], bfr[3];
#pragma unroll
        for (int i = 0; i < 4; ++i) af[i]  = *(const bf16x8*)&sA[wm + i * 16 + lr][lq * 8];
#pragma unroll
        for (int j = 0; j < 3; ++j) bfr[j] = *(const bf16x8*)&sB[wn + j * 16 + lr][lq * 8];
#pragma unroll
        for (int i = 0; i < 4; ++i)
#pragma unroll
            for (int j = 0; j < 3; ++j)
                acc[i][j] = __builtin_amdgcn_mfma_f32_16x16x32_bf16(af[i], bfr[j], acc[i][j], 0, 0, 0);
        __syncthreads();
    }

#pragma unroll
    for (int i = 0; i < 4; ++i)
#pragma unroll
        for (int j = 0; j < 3; ++j) {
            int gn = wn + j * 16 + lr;
#pragma unroll
            for (int r = 0; r < 4; ++r) {
                int gm = m0 + wm + i * 16 + lq * 4 + r;
                unsafeAtomicAdd(&xdbl[(size_t)gm * 96 + gn], acc[i][j][r]);
            }
        }
}

// ---------------------------------------------------------------------------
// K5 (MFMA): dt[4096,2048] = softplus(xdbl[:,0:64] @ Wdt[2048,64]^T + b_dt)
// ---------------------------------------------------------------------------
__global__ __launch_bounds__(256) void dt_mfma(const float* __restrict__ Af,
                                               const float* __restrict__ B,
                                               const float* __restrict__ bdt,
                                               __bf16* __restrict__ dt) {
    __shared__ __align__(16) __bf16 sA[BM][LDK];
    __shared__ __align__(16) __bf16 sB[BN][LDK];
    int tid  = threadIdx.x;
    int wave = tid >> 6, lane = tid & 63;
    int m0 = blockIdx.y * BM, n0 = blockIdx.x * BN;
    int wm = (wave & 1) * 64, wn = (wave >> 1) * 64;
    int lr = lane & 15;
    int lq = lane >> 4;

    floatx4 acc[4][4] = {};

    for (int k0 = 0; k0 < DTRANK; k0 += BK) {
#pragma unroll
        for (int c = tid; c < 512; c += 256) {
            int row = c >> 2, col = (c & 3) * 8;
            const float* src = Af + (size_t)(m0 + row) * 96 + k0 + col;
            floatx4 lo = *(const floatx4*)src;
            floatx4 hi = *(const floatx4*)(src + 4);
            bf16x8 v;
#pragma unroll
            for (int t = 0; t < 4; ++t) { v[t] = (__bf16)lo[t]; v[4 + t] = (__bf16)hi[t]; }
            *(bf16x8*)&sA[row][col] = v;
        }
#pragma unroll
        for (int c = tid; c < 512; c += 256) {
            int row = c >> 2, col = (c & 3) * 8;
            const float* src = B + (size_t)(n0 + row) * DTRANK + k0 + col;
            floatx4 lo = *(const floatx4*)src;
            floatx4 hi = *(const floatx4*)(src + 4);
            bf16x8 v;
#pragma unroll
            for (int t = 0; t < 4; ++t) { v[t] = (__bf16)lo[t]; v[4 + t] = (__bf16)hi[t]; }
            *(bf16x8*)&sB[row][col] = v;
        }
        __syncthreads();

        bf16x8 af[4], bfr[4];
#pragma unroll
        for (int i = 0; i < 4; ++i) af[i]  = *(const bf16x8*)&sA[wm + i * 16 + lr][lq * 8];
#pragma unroll
        for (int j = 0; j < 4; ++j) bfr[j] = *(const bf16x8*)&sB[wn + j * 16 + lr][lq * 8];
#pragma unroll
        for (int i = 0; i < 4; ++i)
#pragma unroll
            for (int j = 0; j < 4; ++j)
                acc[i][j] = __builtin_amdgcn_mfma_f32_16x16x32_bf16(af[i], bfr[j], acc[i][j], 0, 0, 0);
        __syncthreads();
    }

#pragma unroll
    for (int i = 0; i < 4; ++i)
#pragma unroll
        for (int j = 0; j < 4; ++j) {
            int gn = n0 + wn + j * 16 + lr;
            float bv = bdt[gn];
#pragma unroll
            for (int r = 0; r < 4; ++r) {
                int gm = m0 + wm + i * 16 + lq * 4 + r;
                float a = acc[i][j][r] + bv;
                float sp = (a > 20.f) ? a : log1pf(__expf(a));
                dt[(size_t)gm * DINNER + gn] = (__bf16)sp;
            }
        }
}

// ---------------------------------------------------------------------------
// K6 (3-pass chunked scan), LDS-free.
// ---------------------------------------------------------------------------
__global__ __launch_bounds__(64) void scan_pass1(const __bf16* __restrict__ dt,
                                                 const __bf16* __restrict__ u,
                                                 const float* __restrict__ xdbl,
                                                 const float* __restrict__ Alog,
                                                 float* __restrict__ Sdt,
                                                 __bf16* __restrict__ Hfix) {
    int c = blockIdx.x, dblk = blockIdx.y, b = blockIdx.z;
    int lane = threadIdx.x;
    int d = dblk * 64 + lane;
    int row0 = b * SEQ + c * CLEN;

    const __bf16* dtp = dt + (size_t)row0 * DINNER + d;
    const __bf16* up  = u  + (size_t)row0 * DINNER + d;
    const float*  bcp = xdbl + (size_t)row0 * 96 + 64;

    float A[DSTATE], h[DSTATE];
#pragma unroll
    for (int s = 0; s < DSTATE; ++s) { A[s] = -__expf(Alog[d * DSTATE + s]); h[s] = 0.f; }

    float S = 0.f;
    for (int t = 0; t < CLEN; ++t) {
        float dtv = (float)dtp[(size_t)t * DINNER];
        float uv  = (float)up [(size_t)t * DINNER];
        floatx4 B0 = *(const floatx4*)(bcp + t * 96);
        floatx4 B1 = *(const floatx4*)(bcp + t * 96 + 4);
        floatx4 B2 = *(const floatx4*)(bcp + t * 96 + 8);
        floatx4 B3 = *(const floatx4*)(bcp + t * 96 + 12);
        S += dtv;
        float du = dtv * uv;
#pragma unroll
        for (int s = 0; s < 4; ++s) {
            h[s]      = __expf(dtv * A[s])      * h[s]      + du * B0[s];
            h[4 + s]  = __expf(dtv * A[4 + s])  * h[4 + s]  + du * B1[s];
            h[8 + s]  = __expf(dtv * A[8 + s])  * h[8 + s]  + du * B2[s];
            h[12 + s] = __expf(dtv * A[12 + s]) * h[12 + s] + du * B3[s];
        }
    }
    size_t ch = ((size_t)(b * DINNER + d) * CHUNKS + c);
    Sdt[ch] = S;
#pragma unroll
    for (int s = 0; s < DSTATE; ++s) Hfix[ch * DSTATE + s] = (__bf16)h[s];
}

__global__ __launch_bounds__(256) void scan_pass2(const float* __restrict__ Alog,
                                                  const float* __restrict__ Sdt,
                                                  __bf16* __restrict__ Hfix) {
    int g = blockIdx.x * 256 + threadIdx.x;       // over BATCH*DINNER*DSTATE
    int s = g & (DSTATE - 1);
    int bd = g >> 4;
    int d = bd & (DINNER - 1);
    float A = -__expf(Alog[d * DSTATE + s]);
    size_t hbase = (size_t)bd * CHUNKS * DSTATE + s;
    size_t sbase = (size_t)bd * CHUNKS;
    float h = 0.f;
#pragma unroll 4
    for (int c = 0; c < CHUNKS; ++c) {
        float Hl = (float)Hfix[hbase + c * DSTATE];
        float P  = __expf(A * Sdt[sbase + c]);
        Hfix[hbase + c * DSTATE] = (__bf16)h;
        h = P * h + Hl;
    }
}

__global__ __launch_bounds__(64) void scan_pass3(const __bf16* __restrict__ dt,
                                                 const __bf16* __restrict__ u,
                                                 const float* __restrict__ xdbl,
                                                 const float* __restrict__ Alog,
                                                 const float* __restrict__ Dp,
                                                 const __bf16* __restrict__ Hfix,
                                                 __bf16* zy) {
    int c = blockIdx.x, dblk = blockIdx.y, b = blockIdx.z;
    int lane = threadIdx.x;
    int d = dblk * 64 + lane;
    int row0 = b * SEQ + c * CLEN;

    const __bf16* dtp = dt + (size_t)row0 * DINNER + d;
    const __bf16* up  = u  + (size_t)row0 * DINNER + d;
    __bf16*       zyp = zy + (size_t)row0 * DINNER + d;
    const float*  bcp = xdbl + (size_t)row0 * 96 + 64;

    float A[DSTATE], h[DSTATE];
    size_t ch = ((size_t)(b * DINNER + d) * CHUNKS + c);
#pragma unroll
    for (int s = 0; s < DSTATE; ++s) {
        A[s] = -__expf(Alog[d * DSTATE + s]);
        h[s] = (float)Hfix[ch * DSTATE + s];
    }
    float Dv = Dp[d];

    for (int t = 0; t < CLEN; ++t) {
        float dtv = (float)dtp[(size_t)t * DINNER];
        float uv  = (float)up [(size_t)t * DINNER];
        float zv  = (float)zyp[(size_t)t * DINNER];
        floatx4 B0 = *(const floatx4*)(bcp + t * 96);
        floatx4 B1 = *(const floatx4*)(bcp + t * 96 + 4);
        floatx4 B2 = *(const floatx4*)(bcp + t * 96 + 8);
        floatx4 B3 = *(const floatx4*)(bcp + t * 96 + 12);
        floatx4 C0 = *(const floatx4*)(bcp + t * 96 + 16);
        floatx4 C1 = *(const floatx4*)(bcp + t * 96 + 20);
        floatx4 C2 = *(const floatx4*)(bcp + t * 96 + 24);
        floatx4 C3 = *(const floatx4*)(bcp + t * 96 + 28);
        float du = dtv * uv;
        float yv = 0.f;
#pragma unroll
        for (int s = 0; s < 4; ++s) {
            h[s]      = __expf(dtv * A[s])      * h[s]      + du * B0[s];
            h[4 + s]  = __expf(dtv * A[4 + s])  * h[4 + s]  + du * B1[s];
            h[8 + s]  = __expf(dtv * A[8 + s])  * h[8 + s]  + du * B2[s];
            h[12 + s] = __expf(dtv * A[12 + s]) * h[12 + s] + du * B3[s];
            yv += h[s] * C0[s] + h[4 + s] * C1[s] + h[8 + s] * C2[s] + h[12 + s] * C3[s];
        }
        float sg = zv / (1.f + __expf(-zv));
        zyp[(size_t)t * DINNER] = (__bf16)((yv + uv * Dv) * sg);
    }
}

// ---------------------------------------------------------------------------
extern "C" void kernel_launch(void* const* d_in, const int* in_sizes, int n_in,
                              void* d_out, int out_size, void* d_ws, size_t ws_size,
                              hipStream_t stream) {
    const float* x      = (const float*)d_in[0];
    const float* ln_w   = (const float*)d_in[1];
    const float* ln_b   = (const float*)d_in[2];
    const float* W_in   = (const float*)d_in[3];
    const float* conv_w = (const float*)d_in[4];
    const float* conv_b = (const float*)d_in[5];
    const float* W_x    = (const float*)d_in[6];
    const float* W_dt   = (const float*)d_in[7];
    const float* b_dt   = (const float*)d_in[8];
    const float* A_log  = (const float*)d_in[9];
    const float* Dp     = (const float*)d_in[10];
    const float* W_out  = (const float*)d_in[11];
    float* out = (float*)d_out;

    // Workspace, 56 MiB peak:
    //   [ 0,  8M)  xn bf16 (dead after GEMM1) -> { xdbl fp32 [0,1.5M),
    //              Sdt fp32 [1.5M,2M), Hfix bf16 [2M,6M) }
    //   [ 8M,24M)  x_in bf16 (dead after conv) -> dt bf16
    //   [24M,40M)  z bf16; scan pass3 overwrites with y in place
    //   [40M,56M)  Winb bf16 8M (dead after GEMM1) -> u bf16 16M (conv..pass3)
    //              -> Woutb bf16 4M (after pass3)
    char* ws = (char*)d_ws;
    __bf16* xn_bf  = (__bf16*)(ws);
    float*  xdbl   = (float*) (ws);
    float*  Sdt    = (float*) (ws + 1536ull * 1024);
    __bf16* Hfix   = (__bf16*)(ws + (2ull  << 20));
    __bf16* xin_bf = (__bf16*)(ws + (8ull  << 20));
    __bf16* dt_bf  = (__bf16*)(ws + (8ull  << 20));
    __bf16* zy_bf  = (__bf16*)(ws + (24ull << 20));
    __bf16* Winb   = (__bf16*)(ws + (40ull << 20));
    __bf16* u_bf   = (__bf16*)(ws + (40ull << 20));
    __bf16* Woutb  = (__bf16*)(ws + (40ull << 20));

    prep_kernel<<<MROWS + (2 * DINNER * DMODEL) / 1024, 256, 0, stream>>>(
        x, ln_w, ln_b, xn_bf, W_in, Winb);

    gemm_as<1, 8><<<dim3(2 * DINNER / 256, MROWS / 128), 256, 0, stream>>>(
        xn_bf, Winb, MROWS, 2 * DINNER, DMODEL, xin_bf, zy_bf, nullptr, nullptr, DINNER);

    conv_kernel<<<MROWS * DINNER / 256, 256, 0, stream>>>(xin_bf, conv_w, conv_b, u_bf, xdbl);

    wx_mfma<<<dim3(MROWS / BM, WX_KS), 256, 0, stream>>>(u_bf, W_x, xdbl);

    dt_mfma<<<dim3(DINNER / BN, MROWS / BM), 256, 0, stream>>>(xdbl, W_dt, b_dt, dt_bf);

    dim3 sgrid(CHUNKS, DINNER / 64, BATCH);
    scan_pass1<<<sgrid, 64, 0, stream>>>(dt_bf, u_bf, xdbl, A_log, Sdt, Hfix);
    scan_pass2<<<BATCH * DINNER * DSTATE / 256, 256, 0, stream>>>(A_log, Sdt, Hfix);
    scan_pass3<<<sgrid, 64, 0, stream>>>(dt_bf, u_bf, xdbl, A_log, Dp, Hfix, zy_bf);

    w2bf<<<(DMODEL * DINNER) / 1024, 256, 0, stream>>>(W_out, Woutb, DMODEL * DINNER);

    gemm_as<2, 2><<<dim3(DMODEL / 64, MROWS / 128), 256, 0, stream>>>(
        zy_bf, Woutb, MROWS, DMODEL, DINNER, nullptr, nullptr, out, x, 0);
}